// Round 10
// baseline (197.798 us; speedup 1.0000x reference)
//
#include <hip/hip_runtime.h>

// Problem constants (match reference)
constexpr int B    = 64;
constexpr int E    = 512;
constexpr int P    = 31;    // patch size
constexpr int S    = 200;   // canvas size
constexpr int HALF = 15;

// Decomposition: one block per (batch, quarter of emitters); full canvas in LDS
constexpr int QUARTERS = 4;
constexpr int EPQ      = E / QUARTERS;   // 128 emitters per block
constexpr int THREADS  = 1024;           // 16 waves
constexpr int NW       = THREADS / 64;   // 16
constexpr int CANV     = S * S;          // 40000 floats = 156.25 KB LDS

__global__ __launch_bounds__(THREADS, 1)
void imgs4dto3d_scatter_full(const float* __restrict__ img,
                             const int*   __restrict__ xyz,
                             float*       __restrict__ out)
{
    __shared__ float canvas[CANV];       // 160000 B (fits 160 KiB LDS)

    const int q   = blockIdx.x;          // emitter quarter
    const int b   = blockIdx.y;          // batch
    const int tid = threadIdx.x;
    const int wid  = tid >> 6;
    const int lane = tid & 63;

    // ---- zero the canvas ----
    {
        float4* c4 = reinterpret_cast<float4*>(canvas);
        for (int i = tid; i < CANV / 4; i += THREADS)
            c4[i] = make_float4(0.f, 0.f, 0.f, 0.f);
    }
    __syncthreads();

    // lane map: half = row parity (2 rows per iteration), col = 0..31 (31 active)
    const int  half  = lane >> 5;
    const int  col   = lane & 31;
    const bool colok = (col < P);        // lane cols 0..30 active

    // ---- scatter: each wave owns whole emitters (8 each, uniform 961 px) ----
    const int e0 = q * EPQ;
    for (int e8 = 0; e8 < EPQ; e8 += NW) {
        const int e = e0 + e8 + wid;     // wave-uniform
        const int x = xyz[(size_t)(b * E + e) * 3 + 0];
        const int y = xyz[(size_t)(b * E + e) * 3 + 1];

        // per-emitter bases; per-iteration offsets are compile-time constants
        const float* src = img + (size_t)(b * E + e) * (P * P) + half * P + col;
        float*       dst = canvas + (x - HALF + half) * S + (y - HALF + col);

        #pragma unroll
        for (int it = 0; it < 16; ++it) {
            const int  row = 2 * it + half;          // 0..31
            const bool act = colok && (row < P);     // row 31 only at it=15,half=1
            if (act) {
                const float v = src[62 * it];        // img[e][row][col], contiguous
                atomicAdd(dst + 2 * it * S, v);      // canvas[x-15+row][y-15+col]
            }
        }
    }
    __syncthreads();

    // ---- dump: coalesced fire-and-forget global atomics (4 adds per out pixel) ----
    float* ob = out + (size_t)b * CANV;
    for (int i = tid; i < CANV; i += THREADS) {
        atomicAdd(&ob[i], canvas[i]);
    }
}

extern "C" void kernel_launch(void* const* d_in, const int* in_sizes, int n_in,
                              void* d_out, int out_size, void* d_ws, size_t ws_size,
                              hipStream_t stream)
{
    const float* img = (const float*)d_in[0];   // [B, E, P, P] fp32
    const int*   xyz = (const int*)d_in[1];     // [B, E, 3] int32
    float*       out = (float*)d_out;           // [B, 1, S, S] fp32

    // out must start at zero every call (harness poisons it once before timing)
    hipMemsetAsync(out, 0, (size_t)B * CANV * sizeof(float), stream);

    dim3 grid(QUARTERS, B);                     // 256 blocks = 1 per CU
    imgs4dto3d_scatter_full<<<grid, THREADS, 0, stream>>>(img, xyz, out);
}